// Round 1
// 366.533 us; speedup vs baseline: 1.1130x; 1.1130x over previous
//
#include <hip/hip_runtime.h>
#include <hip/hip_bf16.h>

#define BATCH 4096
#define NB    64
#define DM    256
#define KSW   8      // k-steps of W (256/32)
#define KST   10     // total k-steps incl. 2 bias-identity steps (K=320)
#define PBLK  256    // persistent blocks (1 per CU)
#define NTIL  (BATCH / PBLK)   // 16 batch-tiles per block

typedef __bf16 bf16x8 __attribute__((ext_vector_type(8)));
typedef float  f32x4  __attribute__((ext_vector_type(4)));

union Frag16 { uint4 u; bf16x8 b; ushort s[8]; };
union Pk2    { __hip_bfloat162 v; unsigned u; };

__device__ __forceinline__ ushort f2bf(float x) {
    unsigned u = __float_as_uint(x);
    return (ushort)((u + 0x7FFFu + ((u >> 16) & 1u)) >> 16);   // RNE, finite inputs
}
__device__ __forceinline__ unsigned pk2(float a, float b) {
    Pk2 p; p.v = __float22bfloat162_rn(make_float2(a, b));     // v_cvt_pk_bf16_f32 on gfx950
    return p.u;
}
__device__ __forceinline__ float bf2f(ushort u) {
    return __uint_as_float(((unsigned)u) << 16);
}
// VALU-pipe cross-lane add (replaces DS-pipe __shfl_xor for the 16-lane reduce)
template<int CTRL>
__device__ __forceinline__ float dpp_add(float s) {
    int t = __builtin_amdgcn_update_dpp(0, __float_as_int(s), CTRL, 0xF, 0xF, true);
    return s + __int_as_float(t);
}

// ---- pre-pass: swizzle [W ; ba] (K=320) into bf16 B-fragment order ----
// Wf frag idx = (et*10 + ks)*64 + lane ; et = e-tile (0..15), ks = k-step (0..9)
// frag.s[j] = B'[ks*32 + (lane>>4)*8 + j][et*16 + (lane&15)], rows 256..319 = ba
__global__ void swizzle_WB(const float* __restrict__ W, const float* __restrict__ ba,
                           ushort* __restrict__ Wf) {
    int idx  = blockIdx.x * 256 + threadIdx.x;   // 0..10239
    int lane = idx & 63;
    int g    = idx >> 6;                         // 0..159
    int et   = g / KST;
    int ks   = g % KST;
    int e    = et * 16 + (lane & 15);
    int r0   = (ks < KSW) ? ks * 32 : (ks - KSW) * 32;
    r0 += ((lane >> 4) << 3);
    const float* src = (ks < KSW) ? W : ba;
    Frag16 f;
#pragma unroll
    for (int j = 0; j < 8; ++j)
        f.s[j] = f2bf(src[(r0 + j) * DM + e]);
    reinterpret_cast<uint4*>(Wf)[idx] = f.u;
}

// ---- fused: S = tanh([H|I][W;ba]); a = softmax(S, axis=n); out[n] = sum_e a*h ----
// Persistent: 256 blocks x 512 threads (8 waves); each block streams 16 batches
// through a double-buffered LDS tile with register prefetch. W fragments live in
// registers for the whole kernel => the GEMM issues no vmem, so the prefetch's
// vmcnt is never drained early.
__global__ __launch_bounds__(512, 2) void aspect_attn(
    const float*  __restrict__ h,
    const ushort* __restrict__ Wf,
    float*        __restrict__ out)
{
    // H tile in A-fragment order: slot = (mt*8+ks)*64 + lane, 16 B each -> 32768 B
    __shared__ __align__(16) ushort Hs[2][16384];
    __shared__ float op[8][NB];

    const int tid  = threadIdx.x;
    const int wave = tid >> 6;        // 0..7 ; owns S columns [32*wave, 32*wave+32)
    const int lane = tid & 63;
    const int quad = lane >> 4;
    const int l15  = lane & 15;
    const int bid  = blockIdx.x;      // 0..255

    // ---- preload all W fragments for this wave's 2 e-tiles (20 uint4 = 80 VGPR) ----
    const uint4* WfB = reinterpret_cast<const uint4*>(Wf);
    Frag16 wf[2][KST];
#pragma unroll
    for (int nt = 0; nt < 2; ++nt)
#pragma unroll
        for (int ks = 0; ks < KST; ++ks)
            wf[nt][ks].u = WfB[(((wave << 1) | nt) * KST + ks) * 64 + lane];

    // staging geometry: iter 'it' loads frag f = it*8 + wave
    //   row = it*16 + l15 , k0 = wave*32 + quad*8 , LDS uint4 slot = f*64 + lane
    const int sk0 = (wave << 5) | (quad << 3);

    f32x4 pa[4], pc[4];

    // ---- prologue: stage tile 0 ----
    {
        const float* hb = h + (size_t)bid * (NB * DM);
#pragma unroll
        for (int it = 0; it < 4; ++it) {
            const f32x4* p = reinterpret_cast<const f32x4*>(hb + (it * 16 + l15) * DM + sk0);
            pa[it] = p[0]; pc[it] = p[1];
        }
#pragma unroll
        for (int it = 0; it < 4; ++it) {
            uint4 o;
            o.x = pk2(pa[it].x, pa[it].y); o.y = pk2(pa[it].z, pa[it].w);
            o.z = pk2(pc[it].x, pc[it].y); o.w = pk2(pc[it].z, pc[it].w);
            reinterpret_cast<uint4*>(Hs[0])[(it * 8 + wave) * 64 + lane] = o;
        }
    }
    __syncthreads();

#pragma unroll 2
    for (int t = 0; t < NTIL; ++t) {
        const int cur = t & 1;

        // ---- issue prefetch for tile t+1 (results consumed only after the barrier) ----
        if (t + 1 < NTIL) {
            const float* hb = h + (size_t)((t + 1) * PBLK + bid) * (NB * DM);
#pragma unroll
            for (int it = 0; it < 4; ++it) {
                const f32x4* p = reinterpret_cast<const f32x4*>(hb + (it * 16 + l15) * DM + sk0);
                pa[it] = p[0]; pc[it] = p[1];
            }
        }

        // ---- GEMM: wave computes S[0:64][32w : 32w+32], K=320, zero vmem ----
        f32x4 acc[4][2];
#pragma unroll
        for (int mt = 0; mt < 4; ++mt)
#pragma unroll
            for (int nt = 0; nt < 2; ++nt) {
                f32x4 z = {0.f, 0.f, 0.f, 0.f};
                acc[mt][nt] = z;
            }

        const uint4* HsB = reinterpret_cast<const uint4*>(Hs[cur]);
#pragma unroll
        for (int ks = 0; ks < KSW; ++ks) {
            Frag16 af[4];
#pragma unroll
            for (int mt = 0; mt < 4; ++mt)
                af[mt].u = HsB[(mt * 8 + ks) * 64 + lane];
#pragma unroll
            for (int mt = 0; mt < 4; ++mt)
#pragma unroll
                for (int nt = 0; nt < 2; ++nt)
                    acc[mt][nt] = __builtin_amdgcn_mfma_f32_16x16x32_bf16(
                        af[mt].b, wf[nt][ks].b, acc[mt][nt], 0, 0, 0);
        }
        // bias fold: 2 extra k-steps with identity A-fragments (registers only)
#pragma unroll
        for (int kx = 0; kx < 2; ++kx) {
            Frag16 af[4];
            const int kb = kx * 32 + (quad << 3);
#pragma unroll
            for (int mt = 0; mt < 4; ++mt) {
                int d = (mt * 16 + l15) - kb;          // one-hot position, if in [0,8)
#pragma unroll
                for (int j = 0; j < 8; ++j)
                    af[mt].s[j] = (d == j) ? (ushort)0x3F80 : (ushort)0;
            }
#pragma unroll
            for (int mt = 0; mt < 4; ++mt)
#pragma unroll
                for (int nt = 0; nt < 2; ++nt)
                    acc[mt][nt] = __builtin_amdgcn_mfma_f32_16x16x32_bf16(
                        af[mt].b, wf[nt][KSW + kx].b, acc[mt][nt], 0, 0, 0);
        }

        // ---- fused p = exp(tanh(s) - 1); softmax is scale-invariant so the e^-1
        //      factor cancels. 3 trans + 5 VALU per element (was 3 trans + ~11). ----
#pragma unroll
        for (int nt = 0; nt < 2; ++nt) {
            float ls = 0.f;
#pragma unroll
            for (int mt = 0; mt < 4; ++mt)
#pragma unroll
                for (int r = 0; r < 4; ++r) {
                    float x = acc[mt][nt][r];
                    float u = __expf(2.f * x);                              // e^{2s}
                    float p = __expf(-2.f * __builtin_amdgcn_rcpf(u + 1.f)); // e^{tanh-1}
                    acc[mt][nt][r] = p;
                    ls += p;
                }
            ls += __shfl_xor(ls, 16, 64);
            ls += __shfl_xor(ls, 32, 64);
            float inv = __builtin_amdgcn_rcpf(ls);
#pragma unroll
            for (int mt = 0; mt < 4; ++mt)
#pragma unroll
                for (int r = 0; r < 4; ++r)
                    acc[mt][nt][r] *= inv;
        }

        // ---- out[n] = sum_e a[n,e]*h[n,e]; h re-read from frag-order LDS;
        //      16-lane reduce done on the VALU pipe via DPP. ----
        const int colb = wave << 5;
        const ushort* Hc = Hs[cur];
#pragma unroll
        for (int mt = 0; mt < 4; ++mt)
#pragma unroll
            for (int r = 0; r < 4; ++r) {
                const int row  = mt * 16 + (quad << 2) + r;
                const int ridx = mt * 4096 + ((quad << 2) + r) * 8;
                float s = 0.f;
#pragma unroll
                for (int nt = 0; nt < 2; ++nt) {
                    int col  = colb + nt * 16 + l15;
                    int coff = (col >> 5) * 512 + ((col >> 3) & 3) * 128 + (col & 7);
                    s += acc[mt][nt][r] * bf2f(Hc[ridx + coff]);
                }
                s = dpp_add<0xB1>(s);    // xor 1  (quad_perm [1,0,3,2])
                s = dpp_add<0x4E>(s);    // xor 2  (quad_perm [2,3,0,1])
                s = dpp_add<0x141>(s);   // row_half_mirror (combines 4-groups)
                s = dpp_add<0x140>(s);   // row_mirror      (combines 8-groups)
                if (l15 == 0) op[wave][row] = s;
            }
        __syncthreads();   // op published; everyone done reading Hs[cur]

        // ---- commit prefetched tile t+1 into the other buffer (vmcnt waits here) ----
        if (t + 1 < NTIL) {
#pragma unroll
            for (int it = 0; it < 4; ++it) {
                uint4 o;
                o.x = pk2(pa[it].x, pa[it].y); o.y = pk2(pa[it].z, pa[it].w);
                o.z = pk2(pc[it].x, pc[it].y); o.w = pk2(pc[it].z, pc[it].w);
                reinterpret_cast<uint4*>(Hs[cur ^ 1])[(it * 8 + wave) * 64 + lane] = o;
            }
        }

        if (tid < NB) {
            float r = op[0][tid];
#pragma unroll
            for (int w = 1; w < 8; ++w) r += op[w][tid];
            out[(size_t)(t * PBLK + bid) * NB + tid] = r;
        }
        __syncthreads();   // next tile ready; op reusable
    }
}

extern "C" void kernel_launch(void* const* d_in, const int* in_sizes, int n_in,
                              void* d_out, int out_size, void* d_ws, size_t ws_size,
                              hipStream_t stream) {
    const float* h  = (const float*)d_in[0];   // [4096, 64, 256] fp32
    const float* W  = (const float*)d_in[1];   // [256, 256] fp32
    const float* ba = (const float*)d_in[2];   // [64, 256] fp32
    float* out = (float*)d_out;                // [4096, 64] fp32
    ushort* Wf = (ushort*)d_ws;                // 160 KB swizzled bf16 [W ; ba]

    swizzle_WB<<<40, 256, 0, stream>>>(W, ba, Wf);
    aspect_attn<<<PBLK, 512, 0, stream>>>(h, Wf, out);
}

// Round 2
// 365.595 us; speedup vs baseline: 1.1158x; 1.0026x over previous
//
#include <hip/hip_runtime.h>
#include <hip/hip_bf16.h>

#define BATCH 4096
#define NB    64
#define DM    256
#define KSW   8      // k-steps of W (256/32)
#define KST   10     // total k-steps incl. 2 bias-identity steps (K=320)
#define PBLK  256    // persistent blocks (1 per CU)
#define NTIL  (BATCH / PBLK)   // 16 batch-tiles per block

typedef __bf16 bf16x8 __attribute__((ext_vector_type(8)));
typedef float  f32x4  __attribute__((ext_vector_type(4)));

union Frag16 { uint4 u; bf16x8 b; ushort s[8]; };
union Pk2    { __hip_bfloat162 v; unsigned u; };

__device__ __forceinline__ ushort f2bf(float x) {
    unsigned u = __float_as_uint(x);
    return (ushort)((u + 0x7FFFu + ((u >> 16) & 1u)) >> 16);   // RNE, finite inputs
}
__device__ __forceinline__ unsigned pk2(float a, float b) {
    Pk2 p; p.v = __float22bfloat162_rn(make_float2(a, b));     // v_cvt_pk_bf16_f32 on gfx950
    return p.u;
}
__device__ __forceinline__ float bf2f(ushort u) {
    return __uint_as_float(((unsigned)u) << 16);
}
// VALU-pipe cross-lane add (replaces DS-pipe __shfl_xor for the 16-lane reduce)
template<int CTRL>
__device__ __forceinline__ float dpp_add(float s) {
    int t = __builtin_amdgcn_update_dpp(0, __float_as_int(s), CTRL, 0xF, 0xF, true);
    return s + __int_as_float(t);
}

// ---- pre-pass: swizzle [W ; ba] (K=320) into bf16 B-fragment order ----
// Wf frag idx = (et*10 + ks)*64 + lane ; et = e-tile (0..15), ks = k-step (0..9)
// frag.s[j] = B'[ks*32 + (lane>>4)*8 + j][et*16 + (lane&15)], rows 256..319 = ba
__global__ void swizzle_WB(const float* __restrict__ W, const float* __restrict__ ba,
                           ushort* __restrict__ Wf) {
    int idx  = blockIdx.x * 256 + threadIdx.x;   // 0..10239
    int lane = idx & 63;
    int g    = idx >> 6;                         // 0..159
    int et   = g / KST;
    int ks   = g % KST;
    int e    = et * 16 + (lane & 15);
    int r0   = (ks < KSW) ? ks * 32 : (ks - KSW) * 32;
    r0 += ((lane >> 4) << 3);
    const float* src = (ks < KSW) ? W : ba;
    Frag16 f;
#pragma unroll
    for (int j = 0; j < 8; ++j)
        f.s[j] = f2bf(src[(r0 + j) * DM + e]);
    reinterpret_cast<uint4*>(Wf)[idx] = f.u;
}

// ---- fused: S = tanh([H|I][W;ba]); a = softmax(S, axis=n); out[n] = sum_e a*h ----
// Persistent: 256 blocks x 512 threads (8 waves); each block streams 16 batches
// through a double-buffered LDS tile with register prefetch. W fragments live in
// registers for the whole kernel => the GEMM issues no vmem, so the prefetch's
// vmcnt is never drained early. ONE barrier per tile: commit lands pre-barrier
// (disjoint buffer from epilogue reads), out-write lands post-barrier and
// overlaps the next tile's prefetch+GEMM.
__global__ __launch_bounds__(512, 2) void aspect_attn(
    const float*  __restrict__ h,
    const ushort* __restrict__ Wf,
    float*        __restrict__ out)
{
    // H tile in A-fragment order: slot = (mt*8+ks)*64 + lane, 16 B each -> 32768 B
    __shared__ __align__(16) ushort Hs[2][16384];
    __shared__ float op[2][8][NB];

    const int tid  = threadIdx.x;
    const int wave = tid >> 6;        // 0..7 ; owns S columns [32*wave, 32*wave+32)
    const int lane = tid & 63;
    const int quad = lane >> 4;
    const int l15  = lane & 15;
    const int bid  = blockIdx.x;      // 0..255

    // ---- preload all W fragments for this wave's 2 e-tiles (20 uint4 = 80 VGPR) ----
    const uint4* WfB = reinterpret_cast<const uint4*>(Wf);
    Frag16 wf[2][KST];
#pragma unroll
    for (int nt = 0; nt < 2; ++nt)
#pragma unroll
        for (int ks = 0; ks < KST; ++ks)
            wf[nt][ks].u = WfB[(((wave << 1) | nt) * KST + ks) * 64 + lane];

    // staging geometry: iter 'it' loads frag f = it*8 + wave
    //   row = it*16 + l15 , k0 = wave*32 + quad*8 , LDS uint4 slot = f*64 + lane
    const int sk0 = (wave << 5) | (quad << 3);

    f32x4 pa[4], pc[4];

    // ---- prologue: stage tile 0 ----
    {
        const float* hb = h + (size_t)bid * (NB * DM);
#pragma unroll
        for (int it = 0; it < 4; ++it) {
            const f32x4* p = reinterpret_cast<const f32x4*>(hb + (it * 16 + l15) * DM + sk0);
            pa[it] = p[0]; pc[it] = p[1];
        }
#pragma unroll
        for (int it = 0; it < 4; ++it) {
            uint4 o;
            o.x = pk2(pa[it].x, pa[it].y); o.y = pk2(pa[it].z, pa[it].w);
            o.z = pk2(pc[it].x, pc[it].y); o.w = pk2(pc[it].z, pc[it].w);
            reinterpret_cast<uint4*>(Hs[0])[(it * 8 + wave) * 64 + lane] = o;
        }
    }
    __syncthreads();

#pragma unroll 2
    for (int t = 0; t < NTIL; ++t) {
        const int cur = t & 1;

        // ---- issue prefetch for tile t+1 (results consumed only at commit) ----
        if (t + 1 < NTIL) {
            const float* hb = h + (size_t)((t + 1) * PBLK + bid) * (NB * DM);
#pragma unroll
            for (int it = 0; it < 4; ++it) {
                const f32x4* p = reinterpret_cast<const f32x4*>(hb + (it * 16 + l15) * DM + sk0);
                pa[it] = p[0]; pc[it] = p[1];
            }
        }

        // ---- GEMM: wave computes S[0:64][32w : 32w+32], K=320, zero vmem ----
        f32x4 acc[4][2];
#pragma unroll
        for (int mt = 0; mt < 4; ++mt)
#pragma unroll
            for (int nt = 0; nt < 2; ++nt) {
                f32x4 z = {0.f, 0.f, 0.f, 0.f};
                acc[mt][nt] = z;
            }

        const uint4* HsB = reinterpret_cast<const uint4*>(Hs[cur]);
#pragma unroll
        for (int ks = 0; ks < KSW; ++ks) {
            Frag16 af[4];
#pragma unroll
            for (int mt = 0; mt < 4; ++mt)
                af[mt].u = HsB[(mt * 8 + ks) * 64 + lane];
#pragma unroll
            for (int mt = 0; mt < 4; ++mt)
#pragma unroll
                for (int nt = 0; nt < 2; ++nt)
                    acc[mt][nt] = __builtin_amdgcn_mfma_f32_16x16x32_bf16(
                        af[mt].b, wf[nt][ks].b, acc[mt][nt], 0, 0, 0);
        }
        // bias fold: 2 extra k-steps with identity A-fragments (registers only)
#pragma unroll
        for (int kx = 0; kx < 2; ++kx) {
            Frag16 af[4];
            const int kb = kx * 32 + (quad << 3);
#pragma unroll
            for (int mt = 0; mt < 4; ++mt) {
                int d = (mt * 16 + l15) - kb;          // one-hot position, if in [0,8)
#pragma unroll
                for (int j = 0; j < 8; ++j)
                    af[mt].s[j] = (d == j) ? (ushort)0x3F80 : (ushort)0;
            }
#pragma unroll
            for (int mt = 0; mt < 4; ++mt)
#pragma unroll
                for (int nt = 0; nt < 2; ++nt)
                    acc[mt][nt] = __builtin_amdgcn_mfma_f32_16x16x32_bf16(
                        af[mt].b, wf[nt][KSW + kx].b, acc[mt][nt], 0, 0, 0);
        }

        // ---- fused p = exp(tanh(s) - 1); softmax is scale-invariant so the e^-1
        //      factor cancels. 3 trans + 5 VALU per element. ----
#pragma unroll
        for (int nt = 0; nt < 2; ++nt) {
            float ls = 0.f;
#pragma unroll
            for (int mt = 0; mt < 4; ++mt)
#pragma unroll
                for (int r = 0; r < 4; ++r) {
                    float x = acc[mt][nt][r];
                    float u = __expf(2.f * x);                              // e^{2s}
                    float p = __expf(-2.f * __builtin_amdgcn_rcpf(u + 1.f)); // e^{tanh-1}
                    acc[mt][nt][r] = p;
                    ls += p;
                }
            ls += __shfl_xor(ls, 16, 64);
            ls += __shfl_xor(ls, 32, 64);
            float inv = __builtin_amdgcn_rcpf(ls);
#pragma unroll
            for (int mt = 0; mt < 4; ++mt)
#pragma unroll
                for (int r = 0; r < 4; ++r)
                    acc[mt][nt][r] *= inv;
        }

        // ---- out[n] = sum_e a[n,e]*h[n,e]; h re-read from frag-order LDS;
        //      16-lane reduce done on the VALU pipe via DPP. ----
        const int colb = wave << 5;
        const ushort* Hc = Hs[cur];
#pragma unroll
        for (int mt = 0; mt < 4; ++mt)
#pragma unroll
            for (int r = 0; r < 4; ++r) {
                const int row  = mt * 16 + (quad << 2) + r;
                const int ridx = mt * 4096 + ((quad << 2) + r) * 8;
                float s = 0.f;
#pragma unroll
                for (int nt = 0; nt < 2; ++nt) {
                    int col  = colb + nt * 16 + l15;
                    int coff = (col >> 5) * 512 + ((col >> 3) & 3) * 128 + (col & 7);
                    s += acc[mt][nt][r] * bf2f(Hc[ridx + coff]);
                }
                s = dpp_add<0xB1>(s);    // xor 1  (quad_perm [1,0,3,2])
                s = dpp_add<0x4E>(s);    // xor 2  (quad_perm [2,3,0,1])
                s = dpp_add<0x141>(s);   // row_half_mirror (combines 4-groups)
                s = dpp_add<0x140>(s);   // row_mirror      (combines 8-groups)
                if (l15 == 0) op[cur][wave][row] = s;
            }

        // ---- commit prefetched tile t+1 into the other buffer (pre-barrier:
        //      epilogue reads Hs[cur], commit writes Hs[cur^1] — disjoint) ----
        if (t + 1 < NTIL) {
#pragma unroll
            for (int it = 0; it < 4; ++it) {
                uint4 o;
                o.x = pk2(pa[it].x, pa[it].y); o.y = pk2(pa[it].z, pa[it].w);
                o.z = pk2(pc[it].x, pc[it].y); o.w = pk2(pc[it].z, pc[it].w);
                reinterpret_cast<uint4*>(Hs[cur ^ 1])[(it * 8 + wave) * 64 + lane] = o;
            }
        }

        __syncthreads();   // orders: op[cur] published, Hs[cur^1] committed,
                           // all reads of Hs[cur] complete

        // ---- out-write post-barrier: overlaps next tile's prefetch+GEMM.
        //      op[cur] is not rewritten until epi_{t+2}, which is post-B_{t+1}. ----
        if (tid < NB) {
            float r = op[cur][0][tid];
#pragma unroll
            for (int w = 1; w < 8; ++w) r += op[cur][w][tid];
            out[(size_t)(t * PBLK + bid) * NB + tid] = r;
        }
    }
}

extern "C" void kernel_launch(void* const* d_in, const int* in_sizes, int n_in,
                              void* d_out, int out_size, void* d_ws, size_t ws_size,
                              hipStream_t stream) {
    const float* h  = (const float*)d_in[0];   // [4096, 64, 256] fp32
    const float* W  = (const float*)d_in[1];   // [256, 256] fp32
    const float* ba = (const float*)d_in[2];   // [64, 256] fp32
    float* out = (float*)d_out;                // [4096, 64] fp32
    ushort* Wf = (ushort*)d_ws;                // 160 KB swizzled bf16 [W ; ba]

    swizzle_WB<<<40, 256, 0, stream>>>(W, ba, Wf);
    aspect_attn<<<PBLK, 512, 0, stream>>>(h, Wf, out);
}